// Round 5
// baseline (225.820 us; speedup 1.0000x reference)
//
#include <hip/hip_runtime.h>
#include <hip/hip_bf16.h>

// Problem constants (match setup_inputs): N=8192 rows, D=512 dims, C=100 classes.
constexpr int N = 8192;
constexpr int D = 512;
constexpr int C = 100;
constexpr int CAP = 256;             // per-class list capacity (mean 82, ~19 sigma)
constexpr int SLICES = 4;            // dim slices (128 dims each)
constexpr int SLICE_D = D / SLICES;  // 128
constexpr int CHUNKS = 8;            // row chunks per (class, slice)
constexpr int GBLOCKS = C * SLICES * CHUNKS;  // 3200 gather blocks

// Workspace layout (bytes):
//   [0, 400)            counts[C]       (int)    — zeroed by memset
//   [400, 404)          done counter    (int)    — zeroed by memset
//   [512, 205312)       classSum[C][D]  (float)  — zeroed inside norm_kernel
//   [205312, 238080)    invn[N]         (float)
//   [238080, 340480)    list[C][CAP]    (int)
constexpr size_t OFF_CLASSSUM = 512;
constexpr size_t OFF_INVN     = OFF_CLASSSUM + (size_t)C * D * 4;   // 205312
constexpr size_t OFF_LIST     = OFF_INVN + (size_t)N * 4;           // 238080

// K1: one 64-lane wave per row: sum of squares -> inv norm; lane 0 appends
// the row to its class list. Also zeroes classSum (consumed next kernel).
__global__ __launch_bounds__(256) void norm_kernel(
    const float* __restrict__ e,
    const int* __restrict__ y,
    float* __restrict__ invn,
    int* __restrict__ counts,
    int* __restrict__ list,
    float* __restrict__ classSum) {
  const int gid  = blockIdx.x * 256 + threadIdx.x;
  if (gid < C * D) classSum[gid] = 0.0f;  // 51200 elems, first 200 blocks

  const int row  = gid >> 6;
  const int lane = threadIdx.x & 63;
  if (row >= N) return;

  const float4* ep = reinterpret_cast<const float4*>(e + (size_t)row * D);
  const float4 a = ep[lane];
  const float4 b = ep[lane + 64];
  float ss = a.x * a.x + a.y * a.y + a.z * a.z + a.w * a.w
           + b.x * b.x + b.y * b.y + b.z * b.z + b.w * b.w;
  #pragma unroll
  for (int off = 32; off > 0; off >>= 1) ss += __shfl_xor(ss, off);

  if (lane == 0) {
    invn[row] = 1.0f / sqrtf(ss);
    const int c = y[row];
    const int pos = atomicAdd(counts + c, 1);
    if (pos < CAP) list[c * CAP + pos] = row;
  }
}

// K2: one block per (class c, dim-slice s, row-chunk h). Gathers ~n/8 rows,
// accumulates the partial S_c slice in registers, one atomicAdd per element.
// The LAST block to finish (done-counter) computes the final scalar:
//   A = ||sum_c S_c||^2, B = sum_c ||S_c||^2, sq = sum_c n_c^2
//   loss = (A - B) / (N^2 - sq)
__global__ __launch_bounds__(128) void gather_final_kernel(
    const float* __restrict__ e,
    const float* __restrict__ invn,
    const int* __restrict__ counts,
    const int* __restrict__ list,
    float* __restrict__ classSum,
    int* __restrict__ done,
    float* __restrict__ out) {
  const int c   = blockIdx.x / (SLICES * CHUNKS);
  const int rem = blockIdx.x % (SLICES * CHUNKS);
  const int s   = rem / CHUNKS;
  const int h   = rem % CHUNKS;
  const int tid = threadIdx.x;  // 0..127

  int n = counts[c];
  if (n > CAP) n = CAP;
  const int per = (n + CHUNKS - 1) / CHUNKS;   // <= 32
  const int k0  = h * per;
  int k1 = k0 + per;
  if (k1 > n) k1 = n;
  const int m = k1 - k0;

  __shared__ int   ls[CAP / CHUNKS];           // 32
  __shared__ float li[CAP / CHUNKS];
  if (m > 0) {
    if (tid < m) {
      const int r = list[c * CAP + k0 + tid];
      ls[tid] = r;
      li[tid] = invn[r];
    }
    __syncthreads();

    float acc = 0.0f;
    const float* base = e + s * SLICE_D + tid;
    #pragma unroll 4
    for (int k = 0; k < m; ++k) {
      acc += base[(size_t)ls[k] * D] * li[k];
    }
    atomicAdd(classSum + c * D + s * SLICE_D + tid, acc);
  }

  // ---- completion counting (every block, including empty ones) ----
  __threadfence();            // release: our classSum atomics before done++
  __syncthreads();
  __shared__ int lastFlag;
  if (tid == 0) {
    const int old = atomicAdd(done, 1);
    lastFlag = (old == GBLOCKS - 1) ? 1 : 0;
  }
  __syncthreads();
  if (!lastFlag) return;

  // ---- finisher: this block sees all classSum atomics completed ----
  __threadfence();            // acquire
  float Apart = 0.0f, Bpart = 0.0f;
  #pragma unroll
  for (int j = 0; j < 4; ++j) {
    const int d = tid + 128 * j;
    float t = 0.0f, b = 0.0f;
    #pragma unroll 4
    for (int c2 = 0; c2 < C; ++c2) {
      // device-scope atomic load: bypasses this XCD's (possibly stale) L2
      const float v = __hip_atomic_load(classSum + c2 * D + d,
                                        __ATOMIC_RELAXED, __HIP_MEMORY_SCOPE_AGENT);
      t += v;
      b += v * v;
    }
    Apart += t * t;
    Bpart += b;
  }
  #pragma unroll
  for (int off = 32; off > 0; off >>= 1) {
    Apart += __shfl_xor(Apart, off);
    Bpart += __shfl_xor(Bpart, off);
  }
  int q = 0;
  if (tid < C) {
    const int nn = counts[tid];   // written by previous kernel: plain load safe
    q = nn * nn;
  }
  #pragma unroll
  for (int off = 32; off > 0; off >>= 1) q += __shfl_xor(q, off);

  __shared__ float sA[2], sB[2];
  __shared__ int   sQ[2];
  if ((tid & 63) == 0) {
    sA[tid >> 6] = Apart;
    sB[tid >> 6] = Bpart;
    sQ[tid >> 6] = q;
  }
  __syncthreads();
  if (tid == 0) {
    const double A  = (double)sA[0] + (double)sA[1];
    const double B  = (double)sB[0] + (double)sB[1];
    const double sq = (double)(sQ[0] + sQ[1]);
    out[0] = (float)((A - B) / ((double)N * (double)N - sq));
  }
}

extern "C" void kernel_launch(void* const* d_in, const int* in_sizes, int n_in,
                              void* d_out, int out_size, void* d_ws, size_t ws_size,
                              hipStream_t stream) {
  const float* e = (const float*)d_in[0];
  const int*   y = (const int*)d_in[1];
  float* out = (float*)d_out;

  char* ws = (char*)d_ws;
  int*   counts   = (int*)ws;
  int*   done     = (int*)(ws + 400);
  float* classSum = (float*)(ws + OFF_CLASSSUM);
  float* invn     = (float*)(ws + OFF_INVN);
  int*   list     = (int*)(ws + OFF_LIST);

  // ws is re-poisoned to 0xAA before every timed launch — zero counts+done.
  hipMemsetAsync(d_ws, 0, 512, stream);

  norm_kernel<<<N / 4, 256, 0, stream>>>(e, y, invn, counts, list, classSum);
  gather_final_kernel<<<GBLOCKS, 128, 0, stream>>>(e, invn, counts, list,
                                                   classSum, done, out);
}

// Round 7
// 101.138 us; speedup vs baseline: 2.2328x; 2.2328x over previous
//
#include <hip/hip_runtime.h>
#include <hip/hip_bf16.h>

// Problem constants (match setup_inputs): N=8192 rows, D=512 dims, C=100 classes.
constexpr int N = 8192;
constexpr int D = 512;
constexpr int C = 100;
constexpr int CAP = 256;             // per-class list capacity (mean 82, ~19 sigma)
constexpr int SLICES = 4;            // dim slices (128 dims each)
constexpr int SLICE_D = D / SLICES;  // 128
constexpr int CHUNKS = 8;            // row chunks per (class, slice)

// Workspace layout (bytes):
//   [0, 400)            counts[C]       (int)    — zeroed by memset
//   [512, 205312)       classSum[C][D]  (float)  — zeroed inside norm_kernel
//   [205312, 238080)    invn[N]         (float)
//   [238080, 340480)    list[C][CAP]    (int)
constexpr size_t OFF_CLASSSUM = 512;
constexpr size_t OFF_INVN     = OFF_CLASSSUM + (size_t)C * D * 4;   // 205312
constexpr size_t OFF_LIST     = OFF_INVN + (size_t)N * 4;           // 238080

// K1: one 64-lane wave per row: sum of squares -> inv norm; lane 0 appends
// the row to its class list (2 tiny atomics per row). First 200 blocks also
// zero classSum (visibility to K2 via kernel boundary / stream order).
__global__ __launch_bounds__(256) void norm_kernel(
    const float* __restrict__ e,
    const int* __restrict__ y,
    float* __restrict__ invn,
    int* __restrict__ counts,
    int* __restrict__ list,
    float* __restrict__ classSum) {
  const int gid  = blockIdx.x * 256 + threadIdx.x;
  if (gid < C * D) classSum[gid] = 0.0f;  // 51200 elems

  const int row  = gid >> 6;
  const int lane = threadIdx.x & 63;
  if (row >= N) return;

  const float4* ep = reinterpret_cast<const float4*>(e + (size_t)row * D);
  const float4 a = ep[lane];
  const float4 b = ep[lane + 64];
  float ss = a.x * a.x + a.y * a.y + a.z * a.z + a.w * a.w
           + b.x * b.x + b.y * b.y + b.z * b.z + b.w * b.w;
  #pragma unroll
  for (int off = 32; off > 0; off >>= 1) ss += __shfl_xor(ss, off);

  if (lane == 0) {
    invn[row] = 1.0f / sqrtf(ss);
    const int c = y[row];
    const int pos = atomicAdd(counts + c, 1);
    if (pos < CAP) list[c * CAP + pos] = row;
  }
}

// K2: one block per (class c, dim-slice s, row-chunk h). Gathers its ~n/8
// rows, accumulates the partial S_c slice in registers, then ONE atomicAdd
// per element into the zeroed classSum (8-way contention max).
// NO device-scope fences here — round 5 showed per-block __threadfence
// (L2 writeback) costs ~100 µs across 3200 blocks; kernel-boundary
// coherence is the cheap path.
__global__ __launch_bounds__(128) void gather_kernel(
    const float* __restrict__ e,
    const float* __restrict__ invn,
    const int* __restrict__ counts,
    const int* __restrict__ list,
    float* __restrict__ classSum) {
  const int c   = blockIdx.x / (SLICES * CHUNKS);
  const int rem = blockIdx.x % (SLICES * CHUNKS);
  const int s   = rem / CHUNKS;
  const int h   = rem % CHUNKS;
  const int tid = threadIdx.x;  // 0..127, owns dim s*128 + tid

  int n = counts[c];
  if (n > CAP) n = CAP;
  const int per = (n + CHUNKS - 1) / CHUNKS;   // <= 32
  const int k0  = h * per;
  int k1 = k0 + per;
  if (k1 > n) k1 = n;
  const int m = k1 - k0;                       // rows this block handles
  if (m <= 0) return;

  __shared__ int   ls[CAP / CHUNKS];           // 32
  __shared__ float li[CAP / CHUNKS];
  if (tid < m) {
    const int r = list[c * CAP + k0 + tid];
    ls[tid] = r;
    li[tid] = invn[r];
  }
  __syncthreads();

  float acc = 0.0f;
  const float* base = e + s * SLICE_D + tid;
  #pragma unroll 4
  for (int k = 0; k < m; ++k) {
    acc += base[(size_t)ls[k] * D] * li[k];
  }

  atomicAdd(classSum + c * D + s * SLICE_D + tid, acc);
}

// K3: A = ||sum_c S_c||^2, B = sum_c ||S_c||^2, sq = sum_c n_c^2 — all
// parallel LDS-tree reductions.  loss = (A - B) / (N^2 - sq).
__global__ __launch_bounds__(512) void final_kernel(
    const float* __restrict__ classSum,
    const int* __restrict__ counts,
    float* __restrict__ out) {
  const int d = threadIdx.x;  // 0..511, one dim each
  float t = 0.0f, b = 0.0f;
  #pragma unroll 10
  for (int c = 0; c < C; ++c) {
    const float v = classSum[c * D + d];
    t += v;
    b += v * v;
  }
  __shared__ float shA[512];
  __shared__ float shB[512];
  __shared__ float shQ[512];
  shA[d] = t * t;
  shB[d] = b;
  if (d < C) {
    const float n = (float)counts[d];
    shQ[d] = n * n;
  } else {
    shQ[d] = 0.0f;
  }
  __syncthreads();
  for (int off = 256; off > 0; off >>= 1) {
    if (d < off) {
      shA[d] += shA[d + off];
      shB[d] += shB[d + off];
      shQ[d] += shQ[d + off];
    }
    __syncthreads();
  }
  if (d == 0) {
    const double A  = (double)shA[0];
    const double B  = (double)shB[0];
    const double sq = (double)shQ[0];
    out[0] = (float)((A - B) / ((double)N * (double)N - sq));
  }
}

extern "C" void kernel_launch(void* const* d_in, const int* in_sizes, int n_in,
                              void* d_out, int out_size, void* d_ws, size_t ws_size,
                              hipStream_t stream) {
  const float* e = (const float*)d_in[0];
  const int*   y = (const int*)d_in[1];
  float* out = (float*)d_out;

  char* ws = (char*)d_ws;
  int*   counts   = (int*)ws;
  float* classSum = (float*)(ws + OFF_CLASSSUM);
  float* invn     = (float*)(ws + OFF_INVN);
  int*   list     = (int*)(ws + OFF_LIST);

  // ws is re-poisoned to 0xAA before every timed launch — zero counts only
  // (classSum is zeroed inside norm_kernel).
  hipMemsetAsync(d_ws, 0, 512, stream);

  norm_kernel<<<N / 4, 256, 0, stream>>>(e, y, invn, counts, list, classSum);
  gather_kernel<<<C * SLICES * CHUNKS, 128, 0, stream>>>(e, invn, counts, list, classSum);
  final_kernel<<<1, 512, 0, stream>>>(classSum, counts, out);
}

// Round 8
// 86.102 us; speedup vs baseline: 2.6227x; 1.1746x over previous
//
#include <hip/hip_runtime.h>
#include <hip/hip_bf16.h>

// Problem constants (match setup_inputs): N=8192 rows, D=512 dims, C=100 classes.
constexpr int N = 8192;
constexpr int D = 512;
constexpr int C = 100;
constexpr int CAP = 256;             // per-class list capacity (mean 82, ~19 sigma)
constexpr int SLICES = 4;            // dim slices (128 dims each)
constexpr int SLICE_D = D / SLICES;  // 128
constexpr int CHUNKS = 8;            // row chunks per (class, slice)
constexpr int ROWBLKS = N / 4;       // 2048 blocks of 4 waves, one wave per row
constexpr int SCANBLKS = C;          // 100 list-builder blocks (one per class)

// Workspace layout (bytes) — NOTHING needs pre-zeroing (no memset node):
//   [0, 400)            counts[C]       (int)    — plain-stored by K1 scan blocks
//   [512, 205312)       classSum[C][D]  (float)  — zeroed by K1 row blocks
//   [205312, 238080)    invn[N]         (float)
//   [238080, 340480)    list[C][CAP]    (int)
constexpr size_t OFF_CLASSSUM = 512;
constexpr size_t OFF_INVN     = OFF_CLASSSUM + (size_t)C * D * 4;   // 205312
constexpr size_t OFF_LIST     = OFF_INVN + (size_t)N * 4;           // 238080

// K1 (fused, 2148 blocks):
//  - blocks [0, ROWBLKS): one 64-lane wave per row computes inv norm;
//    first 200 blocks also zero classSum (consumed by K2 across the
//    kernel boundary).
//  - blocks [ROWBLKS, ROWBLKS+C): block per class c scans all labels and
//    builds list[c] + counts[c] using only an LDS-local counter — no
//    global atomics, hence no global zero-init required.
__global__ __launch_bounds__(256) void norm_list_kernel(
    const float* __restrict__ e,
    const int* __restrict__ y,
    float* __restrict__ invn,
    int* __restrict__ counts,
    int* __restrict__ list,
    float* __restrict__ classSum) {
  if (blockIdx.x >= ROWBLKS) {
    // ---- list-builder block for class c ----
    const int c = blockIdx.x - ROWBLKS;
    __shared__ int cnt;
    if (threadIdx.x == 0) cnt = 0;
    __syncthreads();
    for (int i = threadIdx.x; i < N; i += 256) {
      if (y[i] == c) {
        const int pos = atomicAdd(&cnt, 1);   // LDS atomic — cheap, block-local
        if (pos < CAP) list[c * CAP + pos] = i;
      }
    }
    __syncthreads();
    if (threadIdx.x == 0) counts[c] = (cnt > CAP) ? CAP : cnt;
    return;
  }

  // ---- row-norm block ----
  const int gid = blockIdx.x * 256 + threadIdx.x;
  if (gid < C * D) classSum[gid] = 0.0f;  // 51200 elems, first 200 blocks

  const int row  = gid >> 6;
  const int lane = threadIdx.x & 63;

  const float4* ep = reinterpret_cast<const float4*>(e + (size_t)row * D);
  const float4 a = ep[lane];
  const float4 b = ep[lane + 64];
  float ss = a.x * a.x + a.y * a.y + a.z * a.z + a.w * a.w
           + b.x * b.x + b.y * b.y + b.z * b.z + b.w * b.w;
  #pragma unroll
  for (int off = 32; off > 0; off >>= 1) ss += __shfl_xor(ss, off);

  if (lane == 0) invn[row] = 1.0f / sqrtf(ss);
}

// K2: one block per (class c, dim-slice s, row-chunk h). Gathers its ~n/8
// rows, accumulates the partial S_c slice in registers, then ONE atomicAdd
// per element into the zeroed classSum (8-way contention max).
// NO device-scope fences here — round 5 showed per-block __threadfence
// (L2 writeback) costs ~100 µs across 3200 blocks; kernel-boundary
// coherence is the cheap path.
__global__ __launch_bounds__(128) void gather_kernel(
    const float* __restrict__ e,
    const float* __restrict__ invn,
    const int* __restrict__ counts,
    const int* __restrict__ list,
    float* __restrict__ classSum) {
  const int c   = blockIdx.x / (SLICES * CHUNKS);
  const int rem = blockIdx.x % (SLICES * CHUNKS);
  const int s   = rem / CHUNKS;
  const int h   = rem % CHUNKS;
  const int tid = threadIdx.x;  // 0..127, owns dim s*128 + tid

  const int n = counts[c];                     // already clamped to CAP
  const int per = (n + CHUNKS - 1) / CHUNKS;   // <= 32
  const int k0  = h * per;
  int k1 = k0 + per;
  if (k1 > n) k1 = n;
  const int m = k1 - k0;                       // rows this block handles
  if (m <= 0) return;

  __shared__ int   ls[CAP / CHUNKS];           // 32
  __shared__ float li[CAP / CHUNKS];
  if (tid < m) {
    const int r = list[c * CAP + k0 + tid];
    ls[tid] = r;
    li[tid] = invn[r];
  }
  __syncthreads();

  float acc = 0.0f;
  const float* base = e + s * SLICE_D + tid;
  #pragma unroll 4
  for (int k = 0; k < m; ++k) {
    acc += base[(size_t)ls[k] * D] * li[k];
  }

  atomicAdd(classSum + c * D + s * SLICE_D + tid, acc);
}

// K3: A = ||sum_c S_c||^2, B = sum_c ||S_c||^2, sq = sum_c n_c^2 — all
// parallel LDS-tree reductions.  loss = (A - B) / (N^2 - sq).
__global__ __launch_bounds__(512) void final_kernel(
    const float* __restrict__ classSum,
    const int* __restrict__ counts,
    float* __restrict__ out) {
  const int d = threadIdx.x;  // 0..511, one dim each
  float t = 0.0f, b = 0.0f;
  #pragma unroll 10
  for (int c = 0; c < C; ++c) {
    const float v = classSum[c * D + d];
    t += v;
    b += v * v;
  }
  __shared__ float shA[512];
  __shared__ float shB[512];
  __shared__ float shQ[512];
  shA[d] = t * t;
  shB[d] = b;
  if (d < C) {
    const float n = (float)counts[d];
    shQ[d] = n * n;
  } else {
    shQ[d] = 0.0f;
  }
  __syncthreads();
  for (int off = 256; off > 0; off >>= 1) {
    if (d < off) {
      shA[d] += shA[d + off];
      shB[d] += shB[d + off];
      shQ[d] += shQ[d + off];
    }
    __syncthreads();
  }
  if (d == 0) {
    const double A  = (double)shA[0];
    const double B  = (double)shB[0];
    const double sq = (double)shQ[0];
    out[0] = (float)((A - B) / ((double)N * (double)N - sq));
  }
}

extern "C" void kernel_launch(void* const* d_in, const int* in_sizes, int n_in,
                              void* d_out, int out_size, void* d_ws, size_t ws_size,
                              hipStream_t stream) {
  const float* e = (const float*)d_in[0];
  const int*   y = (const int*)d_in[1];
  float* out = (float*)d_out;

  char* ws = (char*)d_ws;
  int*   counts   = (int*)ws;
  float* classSum = (float*)(ws + OFF_CLASSSUM);
  float* invn     = (float*)(ws + OFF_INVN);
  int*   list     = (int*)(ws + OFF_LIST);

  // No memset node: counts is plain-stored by K1's scan blocks, classSum is
  // zeroed by K1's row blocks. Nothing reads stale/poisoned ws bytes.
  norm_list_kernel<<<ROWBLKS + SCANBLKS, 256, 0, stream>>>(e, y, invn, counts,
                                                           list, classSum);
  gather_kernel<<<C * SLICES * CHUNKS, 128, 0, stream>>>(e, invn, counts, list,
                                                         classSum);
  final_kernel<<<1, 512, 0, stream>>>(classSum, counts, out);
}